// Round 8
// baseline (480.659 us; speedup 1.0000x reference)
//
#include <hip/hip_runtime.h>

#define NKER  128
#define INDIM 1024
#define UNITS 1024

typedef __attribute__((ext_vector_type(8)))  short          bf16x8;
typedef __attribute__((ext_vector_type(4)))  float          f32x4;
typedef __attribute__((ext_vector_type(4)))  unsigned short u16x4;
typedef __attribute__((ext_vector_type(8)))  unsigned short u16x8;

// Clobber-free waitcnt (guide template form). A "memory" clobber would force
// the backend to conservatively drain vmcnt at every use — the round-1..7 bug.
#define LGKM0   asm volatile("s_waitcnt lgkmcnt(0)")
#define BAR()   __builtin_amdgcn_s_barrier()
#define SCHED0  __builtin_amdgcn_sched_barrier(0)

__device__ __forceinline__ unsigned short f2bf(float f) {
    return __builtin_bit_cast(unsigned short, static_cast<__bf16>(f));
}

// swizzled LDS element index for (row r, k in 0..31) — verified conflict-free
// and numerically correct in rounds 1-7 (SQ_LDS_BANK_CONFLICT == 0)
__device__ __forceinline__ int swzidx(int r, int k) {
    return r * 32 + ((((k >> 3) ^ ((r >> 1) & 3)) << 3) | (k & 7));
}

__global__ void __launch_bounds__(512, 2)
dense_local(const float* __restrict__ X, const float* __restrict__ Kn,
            float* __restrict__ Out)
{
    // [buf][ksub]: A 64KB + B 32KB = 96KB -> 1 wg/CU (by design; overlap is
    // intra-wave via in-flight global loads, not inter-wg)
    __shared__ __align__(16) unsigned short lA[2][2][256 * 32];
    __shared__ __align__(16) unsigned short lB[2][2][128 * 32];

    // XCD swizzle: 2048 wgs, 256/XCD, k-major inside an XCD chunk (bijective)
    const int bid  = blockIdx.x;
    const int wg   = (bid & 7) * 256 + (bid >> 3);
    const int kidx = wg >> 4;
    const int tile = wg & 15;
    const int mt   = tile >> 3;        // 0..1  (M tiles of 256)
    const int nt   = tile & 7;         // 0..7  (N tiles of 128)

    const int t   = threadIdx.x;
    const int l   = t & 63;
    const int w   = t >> 6;            // 0..7
    const int wm  = w >> 1;            // wave m-quadrant (64 rows)
    const int wn  = w & 1;             // wave n-half (64 cols)
    const int l15 = l & 15, g = l >> 4;

    const size_t MROW = (size_t)NKER * INDIM;

    const float* Abase = X   + (size_t)mt * 256 * MROW + (size_t)kidx * INDIM;
    const float* Bbase = Kn  + (size_t)kidx * INDIM * UNITS + nt * 128;
    float*       Cbase = Out + (size_t)mt * 256 * MROW + (size_t)kidx * UNITS + nt * 128;

    // staging maps (verified rounds 1-7)
    const int ar0 = t >> 3;            // A rows 0..63 (+p*64)
    const int ak4 = (t & 7) << 2;      // A k-quad within 32-k subtile
    const int bn  = t & 127;           // B column (lane-consecutive)
    const int bkh = t >> 7;            // B k-octet within 32-k subtile

    const float* aP = Abase + (size_t)ar0 * MROW + ak4;           // +64/tile
    const float* bP = Bbase + (size_t)bkh * 8 * UNITS + bn;       // +64*UNITS/tile

    f32x4 acc[4][4];
#pragma unroll
    for (int mi = 0; mi < 4; ++mi)
#pragma unroll
        for (int ni = 0; ni < 4; ++ni)
            acc[mi][ni] = f32x4{0.f, 0.f, 0.f, 0.f};

    f32x4 SA[4][2];   // A stage regs (one K-tile)
    float SB[2][8];   // B stage regs (one K-tile)

    auto issueA = [&]() {              // 8 x dwordx4
#pragma unroll
        for (int p = 0; p < 4; ++p)
#pragma unroll
            for (int s = 0; s < 2; ++s)
                SA[p][s] = *(const f32x4*)(aP + (size_t)p * 64 * MROW + s * 32);
        aP += 64;
    };
    auto issueB = [&]() {              // 16 x dword, 256B-coalesced per wave
#pragma unroll
        for (int s = 0; s < 2; ++s)
#pragma unroll
            for (int j = 0; j < 8; ++j)
                SB[s][j] = bP[(size_t)(s * 32 + j) * UNITS];
        bP += (size_t)64 * UNITS;
    };
    auto cvtWriteA = [&](int nb) {     // compiler-counted vmcnt lands at cvts
#pragma unroll
        for (int p = 0; p < 4; ++p)
#pragma unroll
            for (int s = 0; s < 2; ++s) {
                u16x4 h;
#pragma unroll
                for (int c = 0; c < 4; ++c) h[c] = f2bf(SA[p][s][c]);
                *(u16x4*)&lA[nb][s][swzidx(ar0 + p * 64, ak4)] = h;
            }
    };
    auto cvtWriteB = [&](int nb) {
#pragma unroll
        for (int s = 0; s < 2; ++s) {
            u16x8 h;
#pragma unroll
            for (int j = 0; j < 8; ++j) h[j] = f2bf(SB[s][j]);
            *(u16x8*)&lB[nb][s][swzidx(bn, bkh * 8)] = h;  // transpose: row=n
        }
    };

    // one K-tile = one phase: frag reads | stage nb | issue tt+2 | MFMA | publish
    auto body = [&](int tt, bool wr, bool iss) {
        const int c = tt & 1, nb = c ^ 1;
        bf16x8 af[4][2], bfv[4][2];
#pragma unroll
        for (int mi = 0; mi < 4; ++mi)
#pragma unroll
            for (int s = 0; s < 2; ++s)
                af[mi][s] = *(const bf16x8*)&lA[c][s][swzidx(wm * 64 + mi * 16 + l15, g * 8)];
#pragma unroll
        for (int ni = 0; ni < 4; ++ni)
#pragma unroll
            for (int s = 0; s < 2; ++s)
                bfv[ni][s] = *(const bf16x8*)&lB[c][s][swzidx(wn * 64 + ni * 16 + l15, g * 8)];
        if (wr)  { cvtWriteA(nb); cvtWriteB(nb); }   // tile tt+1 data
        if (iss) { issueA(); issueB(); }             // tile tt+2 loads
        // no manual wait: compiler inserts COUNTED lgkm/vmcnt at register uses
        __builtin_amdgcn_s_setprio(1);
#pragma unroll
        for (int s = 0; s < 2; ++s)
#pragma unroll
            for (int mi = 0; mi < 4; ++mi)
#pragma unroll
                for (int ni = 0; ni < 4; ++ni)
                    acc[mi][ni] = __builtin_amdgcn_mfma_f32_16x16x32_bf16(
                        af[mi][s], bfv[ni][s], acc[mi][ni], 0, 0, 0);
        __builtin_amdgcn_s_setprio(0);
        SCHED0;          // pin ds_writes above the publish wait
        LGKM0;           // own ds_writes (and reads) complete — vmcnt untouched
        SCHED0;
        BAR();           // publish buf nb / release buf c for overwrite
    };

    // --- prologue: tile0 staged to buf0; tile1 loads left in flight ---
    issueA(); issueB();          // t0
    cvtWriteA(0); cvtWriteB(0);  // waits t0 (counted), stages buf0
    issueA(); issueB();          // t1 — stays in flight across the barrier
    SCHED0;
    LGKM0;
    SCHED0;
    BAR();

    // --- 16 K-tiles: 14 full, 2 peeled ---
#pragma unroll 1
    for (int tt = 0; tt < 14; ++tt)
        body(tt, true, true);
    body(14, true, false);   // stages tile 15, no more issues
    body(15, false, false);  // compute only

    // epilogue: softplus + store (C/D: col=lane&15, row=(lane>>4)*4+reg)
#pragma unroll
    for (int mi = 0; mi < 4; ++mi) {
#pragma unroll
        for (int ni = 0; ni < 4; ++ni) {
            const int n = wn * 64 + ni * 16 + l15;
#pragma unroll
            for (int r = 0; r < 4; ++r) {
                const int m = wm * 64 + mi * 16 + g * 4 + r;
                const float v  = acc[mi][ni][r];
                const float sp = fmaxf(v, 0.0f) + log1pf(__expf(-fabsf(v)));
                Cbase[(size_t)m * MROW + n] = sp;
            }
        }
    }
}

extern "C" void kernel_launch(void* const* d_in, const int* in_sizes, int n_in,
                              void* d_out, int out_size, void* d_ws, size_t ws_size,
                              hipStream_t stream) {
    const float* X  = (const float*)d_in[0];
    const float* Kn = (const float*)d_in[1];
    float* O = (float*)d_out;
    dense_local<<<2048, 512, 0, stream>>>(X, Kn, O);
}

// Round 9
// 479.130 us; speedup vs baseline: 1.0032x; 1.0032x over previous
//
#include <hip/hip_runtime.h>

#define NKER  128
#define INDIM 1024
#define UNITS 1024

typedef __attribute__((ext_vector_type(8)))  short          bf16x8;
typedef __attribute__((ext_vector_type(4)))  float          f32x4;
typedef __attribute__((ext_vector_type(4)))  unsigned short u16x4;
typedef __attribute__((ext_vector_type(8)))  unsigned short u16x8;

#define LGKM0   asm volatile("s_waitcnt lgkmcnt(0)")
#define BAR()   __builtin_amdgcn_s_barrier()
#define SCHED0  __builtin_amdgcn_sched_barrier(0)

__device__ __forceinline__ unsigned short f2bf(float f) {
    return __builtin_bit_cast(unsigned short, static_cast<__bf16>(f));
}

// swizzled LDS element index for (row r, k in 0..31) — verified conflict-free
// and numerically correct in rounds 1-8 (SQ_LDS_BANK_CONFLICT == 0)
__device__ __forceinline__ int swzidx(int r, int k) {
    return r * 32 + ((((k >> 3) ^ ((r >> 1) & 3)) << 3) | (k & 7));
}

__global__ void __launch_bounds__(512, 2)
dense_local(const float* __restrict__ X, const float* __restrict__ Kn,
            float* __restrict__ Out)
{
    // [buf][ksub]: A 64KB + B 32KB = 96KB -> 1 wg/CU; overlap is intra-wave
    __shared__ __align__(16) unsigned short lA[2][2][256 * 32];
    __shared__ __align__(16) unsigned short lB[2][2][128 * 32];

    // XCD swizzle: 2048 wgs, 256/XCD, k-major inside an XCD chunk (bijective)
    const int bid  = blockIdx.x;
    const int wg   = (bid & 7) * 256 + (bid >> 3);
    const int kidx = wg >> 4;
    const int tile = wg & 15;
    const int mt   = tile >> 3;        // 0..1  (M tiles of 256)
    const int nt   = tile & 7;         // 0..7  (N tiles of 128)

    const int t   = threadIdx.x;
    const int l   = t & 63;
    const int w   = t >> 6;            // 0..7
    const int wm  = w >> 1;            // wave m-quadrant (64 rows)
    const int wn  = w & 1;             // wave n-half (64 cols)
    const int l15 = l & 15, g = l >> 4;

    const size_t MROW = (size_t)NKER * INDIM;

    const float* Abase = X   + (size_t)mt * 256 * MROW + (size_t)kidx * INDIM;
    const float* Bbase = Kn  + (size_t)kidx * INDIM * UNITS + nt * 128;
    float*       Cbase = Out + (size_t)mt * 256 * MROW + (size_t)kidx * UNITS + nt * 128;

    // staging maps (verified rounds 1-8)
    const int ar0 = t >> 3;            // A rows 0..63 (+p*64)
    const int ak4 = (t & 7) << 2;      // A k-quad within 32-k subtile
    const int bn  = t & 127;           // B column (lane-consecutive)
    const int bkh = t >> 7;            // B k-octet within 32-k subtile

    const float* aP = Abase + (size_t)ar0 * MROW + ak4;           // +64/tile
    const float* bP = Bbase + (size_t)bkh * 8 * UNITS + bn;       // +64*UNITS/tile

    f32x4 acc[4][4];
#pragma unroll
    for (int mi = 0; mi < 4; ++mi)
#pragma unroll
        for (int ni = 0; ni < 4; ++ni)
            acc[mi][ni] = f32x4{0.f, 0.f, 0.f, 0.f};

    // TWO static stage-set pairs (depth-2): consuming one leaves the other's
    // 24 loads in flight -> the wait is a genuine counted vmcnt(24), and the
    // issue->consume gap is 2 full tile bodies.
    f32x4 SA0[4][2], SA1[4][2];   // 32 VGPR each
    float SB0[2][8], SB1[2][8];   // 16 VGPR each

    auto issueA = [&](f32x4 (&SA)[4][2]) {     // 8 x dwordx4
#pragma unroll
        for (int p = 0; p < 4; ++p)
#pragma unroll
            for (int s = 0; s < 2; ++s)
                SA[p][s] = *(const f32x4*)(aP + (size_t)p * 64 * MROW + s * 32);
        aP += 64;
    };
    auto issueB = [&](float (&SB)[2][8]) {     // 16 x dword, 256B-coalesced
#pragma unroll
        for (int s = 0; s < 2; ++s)
#pragma unroll
            for (int j = 0; j < 8; ++j)
                SB[s][j] = bP[(size_t)(s * 32 + j) * UNITS];
        bP += (size_t)64 * UNITS;
    };
    auto cvtWriteA = [&](const f32x4 (&SA)[4][2], int nb) {
#pragma unroll
        for (int p = 0; p < 4; ++p)
#pragma unroll
            for (int s = 0; s < 2; ++s) {
                u16x4 h;
#pragma unroll
                for (int c = 0; c < 4; ++c) h[c] = f2bf(SA[p][s][c]);
                *(u16x4*)&lA[nb][s][swzidx(ar0 + p * 64, ak4)] = h;
            }
    };
    auto cvtWriteB = [&](const float (&SB)[2][8], int nb) {
#pragma unroll
        for (int s = 0; s < 2; ++s) {
            u16x8 h;
#pragma unroll
            for (int j = 0; j < 8; ++j) h[j] = f2bf(SB[s][j]);
            *(u16x8*)&lB[nb][s][swzidx(bn, bkh * 8)] = h;  // transpose: row=n
        }
    };

    // body(tt): read frags from buf c=tt&1; stage tile tt+1 (loaded 2 bodies
    // ago) into buf nb; reissue the freed set for tile tt+3; MFMA; publish.
    auto body = [&](int c, f32x4 (&SAs)[4][2], float (&SBs)[2][8],
                    bool wr, bool iss) {
        const int nb = c ^ 1;
        bf16x8 af[4][2], bfv[4][2];
#pragma unroll
        for (int mi = 0; mi < 4; ++mi)
#pragma unroll
            for (int s = 0; s < 2; ++s)
                af[mi][s] = *(const bf16x8*)&lA[c][s][swzidx(wm * 64 + mi * 16 + l15, g * 8)];
#pragma unroll
        for (int ni = 0; ni < 4; ++ni)
#pragma unroll
            for (int s = 0; s < 2; ++s)
                bfv[ni][s] = *(const bf16x8*)&lB[c][s][swzidx(wn * 64 + ni * 16 + l15, g * 8)];
        if (wr)  { cvtWriteA(SAs, nb); cvtWriteB(SBs, nb); }  // waits OLDEST 24 only
        if (iss) { issueA(SAs); issueB(SBs); }                // tile tt+3
        __builtin_amdgcn_s_setprio(1);
#pragma unroll
        for (int s = 0; s < 2; ++s)
#pragma unroll
            for (int mi = 0; mi < 4; ++mi)
#pragma unroll
                for (int ni = 0; ni < 4; ++ni)
                    acc[mi][ni] = __builtin_amdgcn_mfma_f32_16x16x32_bf16(
                        af[mi][s], bfv[ni][s], acc[mi][ni], 0, 0, 0);
        __builtin_amdgcn_s_setprio(0);
        SCHED0;
        LGKM0;           // own LDS reads+writes drained (read-release + publish)
        SCHED0;
        BAR();
    };

    // --- prologue: t0,t1 issued; t0 staged (counted wait: t1 stays in flight);
    //     t2 issued into the freed set ---
    issueA(SA0); issueB(SB0);          // t0
    issueA(SA1); issueB(SB1);          // t1
    cvtWriteA(SA0, 0); cvtWriteB(SB0, 0);   // vmcnt(24): waits t0 only
    issueA(SA0); issueB(SB0);          // t2
    SCHED0;
    LGKM0;
    SCHED0;
    BAR();

    // tiles tt=0..15; even bodies work set1, odd bodies set0 (tile parity)
#pragma unroll 1
    for (int it = 0; it < 7; ++it) {
        body(0, SA1, SB1, true, true);      // tt=2it:   stage tt+1, issue tt+3
        body(1, SA0, SB0, true, it < 6);    // tt=2it+1: issue while tt+3 <= 15
    }
    body(0, SA1, SB1, true, false);         // tt=14: stage t15
    body(1, SA0, SB0, false, false);        // tt=15: compute only

    // epilogue: softplus + store (C/D: col=lane&15, row=(lane>>4)*4+reg)
#pragma unroll
    for (int mi = 0; mi < 4; ++mi) {
#pragma unroll
        for (int ni = 0; ni < 4; ++ni) {
            const int n = wn * 64 + ni * 16 + l15;
#pragma unroll
            for (int r = 0; r < 4; ++r) {
                const int m = wm * 64 + mi * 16 + g * 4 + r;
                const float v  = acc[mi][ni][r];
                const float sp = fmaxf(v, 0.0f) + log1pf(__expf(-fabsf(v)));
                Cbase[(size_t)m * MROW + n] = sp;
            }
        }
    }
}

extern "C" void kernel_launch(void* const* d_in, const int* in_sizes, int n_in,
                              void* d_out, int out_size, void* d_ws, size_t ws_size,
                              hipStream_t stream) {
    const float* X  = (const float*)d_in[0];
    const float* Kn = (const float*)d_in[1];
    float* O = (float*)d_out;
    dense_local<<<2048, 512, 0, stream>>>(X, Kn, O);
}

// Round 10
// 450.942 us; speedup vs baseline: 1.0659x; 1.0625x over previous
//
#include <hip/hip_runtime.h>

#define NKER  128
#define INDIM 1024
#define UNITS 1024

typedef __attribute__((ext_vector_type(8))) short          bf16x8;
typedef __attribute__((ext_vector_type(4))) float          f32x4;
typedef __attribute__((ext_vector_type(4))) unsigned int   u32x4;

typedef __attribute__((address_space(1))) const unsigned int gas_t;
typedef __attribute__((address_space(3)))       unsigned int las_t;
#define GLOAD16(g, l) \
    __builtin_amdgcn_global_load_lds((gas_t*)(g), (las_t*)(l), 16, 0, 0)

// fp32 -> bf16 (round-half-up) pair-pack via byte-perm: 2 VALU per element,
// no __bf16 cast lowering, no sub-word ops. low u16 = lo, high u16 = hi.
__device__ __forceinline__ unsigned int bpack2(float lo, float hi) {
    unsigned int ul = __builtin_bit_cast(unsigned int, lo) + 0x8000u;
    unsigned int uh = __builtin_bit_cast(unsigned int, hi) + 0x8000u;
    return __builtin_amdgcn_perm(uh, ul, 0x07060302u);
}

// swizzled LDS element index for B (row r=n, k in 0..31) — verified
// conflict-free + numerically correct, rounds 1-9
__device__ __forceinline__ int swzidx(int r, int k) {
    return r * 32 + ((((k >> 3) ^ ((r >> 1) & 3)) << 3) | (k & 7));
}

__global__ void __launch_bounds__(256, 3)
dense_local(const float* __restrict__ X, const float* __restrict__ Kn,
            float* __restrict__ Out)
{
    // A: fp32, linear rows of 128B, filled by global_load_lds (src pre-XOR'd)
    // B: bf16 transposed+swizzled (reg-staged).  Total 48KB -> 3 wgs/CU.
    __shared__ __align__(16) float          lAf[2][128 * 32];
    __shared__ __align__(16) unsigned short lB [2][128 * 32];

    // XCD swizzle: 4096 wgs, 512/XCD, k-major in chunk (R1-verified)
    const int bid  = blockIdx.x;
    const int wg   = (bid & 7) * 512 + (bid >> 3);
    const int kidx = wg >> 5;
    const int tile = wg & 31;
    const int mt   = tile >> 3;        // 0..3 (M tiles of 128)
    const int nt   = tile & 7;         // 0..7 (N tiles of 128)

    const int t   = threadIdx.x;
    const int l   = t & 63;
    const int w   = t >> 6;            // 0..3
    const int wr  = w >> 1, wc = w & 1;
    const int l15 = l & 15, g = l >> 4;

    const size_t MROW = (size_t)NKER * INDIM;

    const float* Abase = X   + (size_t)mt * 128 * MROW + (size_t)kidx * INDIM;
    const float* Bbase = Kn  + (size_t)kidx * INDIM * UNITS + nt * 128;
    float*       Cbase = Out + (size_t)mt * 128 * MROW + (size_t)kidx * UNITS + nt * 128;

    // ---- A gload map: group (w*4+j) covers rows +0..7; lane>>3 = row-in-8,
    //      lane&7 = LDS 16B chunk; global chunk = (lane&7) ^ (row&7) ----
    const int  rlo  = (t >> 3) & 7;
    const int  cgl  = (t & 7) ^ rlo;                  // source pre-swizzle
    const float* aG = Abase + (size_t)(w * 32 + rlo) * MROW + cgl * 4;
    const size_t MR8 = (size_t)8 * MROW;

    // ---- B staging map (R1-verified, 256 thr) ----
    const int bn  = ((w & 1) << 6) | l;               // 0..127
    const int bkh = w >> 1;                           // 0..1
    const float* bG = Bbase + (size_t)(bkh * 16) * UNITS + bn;

    f32x4 acc[4][4];
#pragma unroll
    for (int mi = 0; mi < 4; ++mi)
#pragma unroll
        for (int ni = 0; ni < 4; ++ni)
            acc[mi][ni] = f32x4{0.f, 0.f, 0.f, 0.f};

    float bv[16];

    auto gloadA = [&](int nb) {        // 4 fire-and-forget instrs, no regs
        GLOAD16(aG,            &lAf[nb][(w * 4 + 0) * 256]);
        GLOAD16(aG + MR8,      &lAf[nb][(w * 4 + 1) * 256]);
        GLOAD16(aG + 2 * MR8,  &lAf[nb][(w * 4 + 2) * 256]);
        GLOAD16(aG + 3 * MR8,  &lAf[nb][(w * 4 + 3) * 256]);
        aG += 32;                      // next K-tile
    };
    auto loadB = [&]() {
#pragma unroll
        for (int j = 0; j < 16; ++j)
            bv[j] = bG[(size_t)j * UNITS];   // 256B-coalesced per wave
        bG += (size_t)32 * UNITS;
    };
    auto writeB = [&](int nb) {        // counted-vmcnt wait lands at the packs
        u32x4 W0{bpack2(bv[0], bv[1]),  bpack2(bv[2], bv[3]),
                 bpack2(bv[4], bv[5]),  bpack2(bv[6], bv[7])};
        u32x4 W1{bpack2(bv[8], bv[9]),  bpack2(bv[10], bv[11]),
                 bpack2(bv[12], bv[13]), bpack2(bv[14], bv[15])};
        *(u32x4*)&lB[nb][swzidx(bn, bkh * 16)]     = W0;
        *(u32x4*)&lB[nb][swzidx(bn, bkh * 16 + 8)] = W1;
    };

    auto compute = [&](int c) {
        bf16x8 af[4], bfr[4];
#pragma unroll
        for (int mi = 0; mi < 4; ++mi) {
            const int arow = wr * 64 + mi * 16 + l15;
            const int ax   = l15 & 7;
            const float* pa = &lAf[c][arow * 32];
            f32x4 v0 = *(const f32x4*)(pa + ((( 2 * g)      ^ ax) << 2));
            f32x4 v1 = *(const f32x4*)(pa + (((2 * g + 1)   ^ ax) << 2));
            u32x4 pw{bpack2(v0[0], v0[1]), bpack2(v0[2], v0[3]),
                     bpack2(v1[0], v1[1]), bpack2(v1[2], v1[3])};
            af[mi] = __builtin_bit_cast(bf16x8, pw);
        }
#pragma unroll
        for (int ni = 0; ni < 4; ++ni)
            bfr[ni] = *(const bf16x8*)&lB[c][swzidx(wc * 64 + ni * 16 + l15, g * 8)];
        __builtin_amdgcn_s_setprio(1);
#pragma unroll
        for (int mi = 0; mi < 4; ++mi)
#pragma unroll
            for (int ni = 0; ni < 4; ++ni)
                acc[mi][ni] = __builtin_amdgcn_mfma_f32_16x16x32_bf16(
                    af[mi], bfr[ni], acc[mi][ni], 0, 0, 0);
        __builtin_amdgcn_s_setprio(0);
    };

    // --- prologue: tile 0 -> buf 0 ---
    gloadA(0);
    loadB();
    writeB(0);
    __syncthreads();

    // --- 32 K-tiles, unrolled x2 for static buffer indices ---
#pragma unroll 1
    for (int it = 0; it < 16; ++it) {
        // even tile 2it (buf 0); prefetch tile 2it+1 -> buf 1 (always exists)
        gloadA(1);
        loadB();
        compute(0);
        writeB(1);
        __syncthreads();
        // odd tile 2it+1 (buf 1); prefetch tile 2it+2 -> buf 0
        if (it < 15) { gloadA(0); loadB(); }
        compute(1);
        if (it < 15) writeB(0);
        __syncthreads();
    }

    // epilogue: softplus + store (C/D: col=lane&15, row=(lane>>4)*4+reg)
#pragma unroll
    for (int mi = 0; mi < 4; ++mi) {
#pragma unroll
        for (int ni = 0; ni < 4; ++ni) {
            const int n = wc * 64 + ni * 16 + l15;
#pragma unroll
            for (int r = 0; r < 4; ++r) {
                const int m = wr * 64 + mi * 16 + g * 4 + r;
                const float v  = acc[mi][ni][r];
                const float sp = fmaxf(v, 0.0f) + log1pf(__expf(-fabsf(v)));
                Cbase[(size_t)m * MROW + n] = sp;
            }
        }
    }
}

extern "C" void kernel_launch(void* const* d_in, const int* in_sizes, int n_in,
                              void* d_out, int out_size, void* d_ws, size_t ws_size,
                              hipStream_t stream) {
    const float* X  = (const float*)d_in[0];
    const float* Kn = (const float*)d_in[1];
    float* O = (float*)d_out;
    dense_local<<<4096, 256, 0, stream>>>(X, Kn, O);
}